// Round 6
// baseline (557.293 us; speedup 1.0000x reference)
//
#include <hip/hip_runtime.h>
#include <hip/hip_cooperative_groups.h>
#include <math.h>

namespace cg = cooperative_groups;

#define NA 10000
#define NE 40000
#define NTILE 1250   // 32-edge MFMA tiles (CSR order)
#define NWIN  1250   // 32-edge softmax windows

typedef float f4 __attribute__((ext_vector_type(4)));
typedef float f16v __attribute__((ext_vector_type(16)));
typedef __bf16 bf16x8 __attribute__((ext_vector_type(8)));

union U8 { unsigned short us[8]; bf16x8 v; };

static __device__ __forceinline__ unsigned short bf_rne(float x){
  unsigned u = __float_as_uint(x);
  unsigned r = (u + 0x7fffu + ((u>>16)&1u)) >> 16;
  return (unsigned short)r;
}
static __device__ __forceinline__ float bf_to_f(unsigned short h){
  return __uint_as_float(((unsigned)h)<<16);
}

// ---------------- phase: fold BN into weights, build tables ----------------
static __device__ void phase_fold(int gid, int gstride,
  const float* __restrict__ encW, const float* __restrict__ encB,
  const float* __restrict__ eg, const float* __restrict__ ebt,
  const float* __restrict__ e_mn, const float* __restrict__ e_vr,
  const float* __restrict__ attW, const float* __restrict__ attB,
  const float* __restrict__ agm, const float* __restrict__ abt,
  const float* __restrict__ amn, const float* __restrict__ avr,
  const float* __restrict__ wih, const float* __restrict__ whh,
  unsigned short* __restrict__ Bh, unsigned short* __restrict__ Bl,
  float* __restrict__ attWt, float* __restrict__ attBf, float* __restrict__ wT)
{
  for (int i=gid; i<65536; i+=gstride){
    int j = i&7, ll = (i>>3)&63, t = i>>9;
    int d = t>>1, ft = t&1;
    int k = ((ll>>5)<<3)+j;
    int n = d*64 + ft*32 + (ll&31);
    float s = eg[n]*rsqrtf(e_vr[n]+1e-6f);
    unsigned short vh=0, vl=0;
    if (k<12){
      float wv = encW[n*12+k]*s;
      unsigned short hi = bf_rne(wv);
      vh = hi; vl = bf_rne(wv - bf_to_f(hi));
    } else if (k==12){
      float b = (encB[n]-e_mn[n])*s + ebt[n];
      unsigned short hi = bf_rne(b);
      vh = hi; vl = bf_rne(b - bf_to_f(hi));
    }
    Bh[i] = vh; Bl[i] = vl;
  }
  for (int i=gid; i<4096; i+=gstride){
    int k = i>>6, f = i&63;
    float s = agm[f]*rsqrtf(avr[f]+1e-6f);
    attWt[i] = attW[f*64+k]*s;
  }
  for (int f=gid; f<64; f+=gstride){
    float s = agm[f]*rsqrtf(avr[f]+1e-6f);
    attBf[f] = (attB[f]-amn[f])*s + abt[f];
  }
  for (int i=gid; i<24576; i+=gstride){
    int k=i/384, rem=i-k*384, g=rem>>6, f=rem&63;
    wT[i] = (g<3)? wih[(g*64+f)*64+k] : whh[((g-3)*64+f)*64+k];
  }
}

// ---------------- phase: exclusive scan (single block, 1KB LDS) ----------------
static __device__ void phase_scan(int tid, const int* __restrict__ cnt,
                                  int* __restrict__ rowstart, int* __restrict__ wofs,
                                  int* sPart)
{
  int lo = tid*40, hi = lo+40;
  if (hi>NA) hi=NA; if (lo>NA) lo=NA;
  int sum=0;
  for (int i=lo;i<hi;i++) sum += cnt[i];
  sPart[tid]=sum;
  __syncthreads();
  for (int off=1; off<256; off<<=1){
    int v = (tid>=off)? sPart[tid-off] : 0;
    __syncthreads();
    sPart[tid]+=v;
    __syncthreads();
  }
  int run = sPart[tid]-sum;
  for (int i=lo;i<hi;i++){
    int c = cnt[i];
    rowstart[i]=run; wofs[i]=run;
    run += c;
  }
  if (tid==255) rowstart[NA]=NE;
}

// ---------------- phase: scatter edges to CSR + window table ----------------
static __device__ void phase_scatter(int gid, int gstride,
  const int* __restrict__ bidx, int* __restrict__ wofs, int* __restrict__ elist,
  const int* __restrict__ rowstart, int* __restrict__ aLoTab)
{
  for (int e=gid; e<NE; e+=gstride){
    int tg = bidx[e*2];
    int pos = atomicAdd(&wofs[tg],1);
    elist[pos]=e;
  }
  // aLoTab[t] = min{a : rowstart[a] >= 32 t}, t in [0, NWIN]
  for (int a=gid; a<=NA; a+=gstride){
    int rc = rowstart[a];
    int tlo = (a==0)? 0 : ((rowstart[a-1]>>5)+1);
    int thi = rc>>5;
    for (int t=tlo; t<=thi && t<=NWIN; t++) aLoTab[t]=a;
  }
}

// ---------------- phase: MFMA enc GEMM + contraction, one 32-edge CSR tile ----------------
static __device__ void phase_edge(int tid, int tile,
  const float* __restrict__ atom, const int* __restrict__ bidx, const float* __restrict__ bond,
  const unsigned short* __restrict__ Bh, const unsigned short* __restrict__ Bl,
  const int* __restrict__ elist, float* __restrict__ nbC,
  float* smem, int* sInt)
{
  float* sA = smem;          // 2112: atomT [d(64)][stride 33]
  float* sP = smem + 2112;   // 4096: one ft-round of wave partials
  int* sEl  = sInt;          // 32
  int* sNbr = sInt + 32;     // 32
  int l = tid&63, w = tid>>6, g = l>>5, em = l&31;
  int E0 = tile*32;
  __syncthreads();
  if (tid < 32){
    int e = elist[E0+tid];
    sEl[tid] = e;
    sNbr[tid] = bidx[e*2+1];
  }
  __syncthreads();
  for (int i=tid; i<2048; i+=256){
    int le=i>>6, d=i&63;
    sA[d*33+le] = atom[(size_t)sNbr[le]*64 + d];
  }
  // A fragments: edge row em, k = g*8+j; hi/lo split; bias slot k=12
  U8 A1, A2;
  {
    const f4* bp = (const f4*)(bond + (size_t)sEl[em]*12);
    f4 b0=bp[0], b1v=bp[1], b2v=bp[2];
    float bv[12] = {b0.x,b0.y,b0.z,b0.w,b1v.x,b1v.y,b1v.z,b1v.w,b2v.x,b2v.y,b2v.z,b2v.w};
    unsigned short hi[12], lo2[12];
    #pragma unroll
    for (int j=0;j<12;j++){ hi[j]=bf_rne(bv[j]); lo2[j]=bf_rne(bv[j]-bf_to_f(hi[j])); }
    #pragma unroll
    for (int j=0;j<8;j++){
      int k = g*8+j;
      A1.us[j] = (k<12)? hi[k] : (k==12? (unsigned short)0x3F80 : (unsigned short)0);
      A2.us[j] = (k<12)? lo2[k] : (unsigned short)0;
    }
  }
  __syncthreads();

  f4 nacc[2][4];
  #pragma unroll
  for (int ft=0; ft<2; ft++)
    #pragma unroll
    for (int q=0;q<4;q++) nacc[ft][q] = (f4){0.f,0.f,0.f,0.f};
  f16v cz;
  #pragma unroll
  for (int r=0;r<16;r++) cz[r] = 0.f;

  int dbase = w*16;
  for (int dd=0; dd<16; dd++){
    int d = dbase + dd;
    f4 ldA[4];
    #pragma unroll
    for (int q=0;q<4;q++) ldA[q] = *(const f4*)&sA[d*33 + 8*q + 4*g];
    #pragma unroll
    for (int ft=0; ft<2; ft++){
      U8 bbh, bbl;
      bbh.v = *(const bf16x8*)(Bh + ((size_t)((d*2+ft)*64 + l))*8);
      bbl.v = *(const bf16x8*)(Bl + ((size_t)((d*2+ft)*64 + l))*8);
      f16v c;
      c = __builtin_amdgcn_mfma_f32_32x32x16_bf16(A1.v, bbh.v, cz, 0,0,0);
      c = __builtin_amdgcn_mfma_f32_32x32x16_bf16(A2.v, bbh.v, c, 0,0,0);
      c = __builtin_amdgcn_mfma_f32_32x32x16_bf16(A1.v, bbl.v, c, 0,0,0);
      #pragma unroll
      for (int r=0;r<16;r++){
        float ev = fmaxf(c[r], 0.f);
        nacc[ft][r>>2][r&3] = fmaf(ldA[r>>2][r&3], ev, nacc[ft][r>>2][r&3]);
      }
    }
  }

  // two dump/reduce rounds (16KB sP), write nbC by CSR position
  #pragma unroll
  for (int ft=0; ft<2; ft++){
    __syncthreads();
    #pragma unroll
    for (int r=0;r<16;r++)
      sP[w*1024 + r*64 + l] = nacc[ft][r>>2][r&3];
    __syncthreads();
    for (int idx=tid; idx<1024; idx+=256){
      float v = sP[idx] + sP[1024+idx] + sP[2048+idx] + sP[3072+idx];
      int r = idx>>6, ll = idx&63;
      int m = (r&3) + ((r>>2)<<3) + ((ll>>5)<<2);
      int f = (ft<<5) + (ll&31);
      nbC[(size_t)(E0+m)*64 + f] = v;
    }
  }
}

// ---------------- phase: window softmax + linearized context + ELU + in-wave GRU ----------------
static __device__ void phase_window(int tid, int vb,
  const float* __restrict__ atom, const float* __restrict__ alW, const float* __restrict__ alB,
  const float* __restrict__ attWt, const float* __restrict__ attBf, const float* __restrict__ wT,
  const float* __restrict__ bih, const float* __restrict__ bhh,
  const int* __restrict__ rowstart, const int* __restrict__ aLoTab,
  const float* __restrict__ nbC, float* __restrict__ out, float* smem)
{
  float* sNbE = smem;         // 96 x 64
  float* sQ   = smem + 6144;  // 96
  int l = tid&63, w = tid>>6;
  __syncthreads();
  int aLo = aLoTab[vb], aHi = aLoTab[vb+1];
  int E0 = rowstart[aLo];
  int nE = rowstart[aHi] - E0;
  if (nE > 96) nE = 96;
  float wnl = alW[64+l];
  for (int le = w; le < nE; le += 4){
    float v = nbC[(size_t)(E0+le)*64 + l];
    sNbE[le*64 + l] = v;
    float q = wnl*v;
    q += __shfl_xor(q,1); q += __shfl_xor(q,2); q += __shfl_xor(q,4);
    q += __shfl_xor(q,8); q += __shfl_xor(q,16); q += __shfl_xor(q,32);
    if (l==0) sQ[le] = q;
  }
  __syncthreads();
  float wa = alW[l], ab = alB[0], bfv = attBf[l];
  float b0=bih[l], b1=bih[64+l], b2=bih[128+l];
  float h0=bhh[l], h1=bhh[64+l], h2=bhh[128+l];
  for (int a0 = aLo + w; a0 < aHi; a0 += 16){
    float cfb[4], hfb[4];
    #pragma unroll
    for (int ii=0; ii<4; ii++){
      int a = a0 + ii*4;
      float cf=0.f, hf=0.f;
      if (a < aHi){
        hf = atom[(size_t)a*64 + l];
        int d0 = rowstart[a], d1 = rowstart[a+1];
        int deg = d1-d0, le0 = d0-E0;
        if (deg > 0){
          float p = wa*hf;
          p += __shfl_xor(p,1); p += __shfl_xor(p,2); p += __shfl_xor(p,4);
          p += __shfl_xor(p,8); p += __shfl_xor(p,16); p += __shfl_xor(p,32);
          float mx = -1e30f;
          for (int i=0;i<deg;i++){
            float s = p + sQ[le0+i] + ab;
            s = (s>0.f)? s : 0.01f*s;
            mx = fmaxf(mx, s);
          }
          float dn=0.f, y=0.f;
          for (int i=0;i<deg;i++){
            float s = p + sQ[le0+i] + ab;
            s = (s>0.f)? s : 0.01f*s;
            float ex = __expf(s-mx);
            dn += ex;
            y = fmaf(ex, sNbE[(le0+i)*64 + l], y);
          }
          float ctx = dn*bfv;
          #pragma unroll 8
          for (int k=0;k<64;k++)
            ctx = fmaf(__shfl(y,k), attWt[k*64+l], ctx);
          cf = ctx/(dn+1e-8f);
          cf = (cf>0.f)? cf : expm1f(cf);
        }
      }
      cfb[ii]=cf; hfb[ii]=hf;
    }
    // in-wave GRU for up to 4 atoms
    float acc[6][4];
    #pragma unroll
    for (int gg=0; gg<6; gg++)
      #pragma unroll
      for (int ii=0; ii<4; ii++) acc[gg][ii]=0.f;
    for (int k=0;k<64;k++){
      const float* wr = wT + k*384 + l;
      float w0=wr[0], w1=wr[64], w2=wr[128], w3=wr[192], w4=wr[256], w5=wr[320];
      #pragma unroll
      for (int ii=0; ii<4; ii++){
        float ck = __shfl(cfb[ii], k);
        float hk = __shfl(hfb[ii], k);
        acc[0][ii] = fmaf(ck,w0,acc[0][ii]);
        acc[1][ii] = fmaf(ck,w1,acc[1][ii]);
        acc[2][ii] = fmaf(ck,w2,acc[2][ii]);
        acc[3][ii] = fmaf(hk,w3,acc[3][ii]);
        acc[4][ii] = fmaf(hk,w4,acc[4][ii]);
        acc[5][ii] = fmaf(hk,w5,acc[5][ii]);
      }
    }
    #pragma unroll
    for (int ii=0; ii<4; ii++){
      int a = a0 + ii*4;
      if (a < aHi){
        float r = 1.f/(1.f + expf(-(acc[0][ii] + b0 + acc[3][ii] + h0)));
        float z = 1.f/(1.f + expf(-(acc[1][ii] + b1 + acc[4][ii] + h1)));
        float n = tanhf(acc[2][ii] + b2 + r*(acc[5][ii] + h2));
        out[(size_t)a*64 + l] = (1.f - z)*n + z*hfb[ii];
      }
    }
  }
}

// ================= cooperative mega-kernel =================
__global__ __launch_bounds__(256, 2) void k_mega(
  const float* atom, const int* bidx, const float* bond,
  const float* encW, const float* encB, const float* eg, const float* ebt,
  const float* e_mn, const float* e_vr,
  const float* attW, const float* attB, const float* agm, const float* abt,
  const float* amn, const float* avr,
  const float* alW, const float* alB,
  const float* wih, const float* whh, const float* bih, const float* bhh,
  unsigned short* Bh, unsigned short* Bl, float* attWt, float* attBf, float* wT,
  int* cnt, int* rowstart, int* wofs, int* elist, int* aLoTab,
  float* nbC, float* out)
{
  cg::grid_group grid = cg::this_grid();
  __shared__ float smem[6400];
  __shared__ int   sInt[320];
  int tid = threadIdx.x, bb = blockIdx.x, nb = gridDim.x;
  int gid = bb*256 + tid, gstride = nb*256;

  phase_fold(gid,gstride,encW,encB,eg,ebt,e_mn,e_vr,attW,attB,agm,abt,amn,avr,
             wih,whh,Bh,Bl,attWt,attBf,wT);
  for (int i=gid; i<NA; i+=gstride) cnt[i]=0;
  grid.sync();
  for (int e=gid; e<NE; e+=gstride) atomicAdd(&cnt[bidx[e*2]],1);
  grid.sync();
  if (bb==0) phase_scan(tid, cnt, rowstart, wofs, sInt+64);
  grid.sync();
  phase_scatter(gid,gstride,bidx,wofs,elist,rowstart,aLoTab);
  grid.sync();
  for (int t=bb; t<NTILE; t+=nb)
    phase_edge(tid,t,atom,bidx,bond,Bh,Bl,elist,nbC,smem,sInt);
  grid.sync();
  for (int v=bb; v<NWIN; v+=nb)
    phase_window(tid,v,atom,alW,alB,attWt,attBf,wT,bih,bhh,rowstart,aLoTab,nbC,out,smem);
}

// ================= fallback wrappers =================
__global__ __launch_bounds__(256) void k_pre_w(
  const float* encW, const float* encB, const float* eg, const float* ebt,
  const float* e_mn, const float* e_vr,
  const float* attW, const float* attB, const float* agm, const float* abt,
  const float* amn, const float* avr,
  const float* wih, const float* whh, const int* bidx,
  unsigned short* Bh, unsigned short* Bl, float* attWt, float* attBf, float* wT,
  int* cnt)
{
  int gid = blockIdx.x*256 + threadIdx.x, gstride = gridDim.x*256;
  phase_fold(gid,gstride,encW,encB,eg,ebt,e_mn,e_vr,attW,attB,agm,abt,amn,avr,
             wih,whh,Bh,Bl,attWt,attBf,wT);
  for (int e=gid; e<NE; e+=gstride) atomicAdd(&cnt[bidx[e*2]],1);
}

__global__ __launch_bounds__(256) void k_scan_w(const int* cnt, int* rowstart, int* wofs){
  __shared__ int sPart[256];
  phase_scan(threadIdx.x, cnt, rowstart, wofs, sPart);
}

__global__ __launch_bounds__(256) void k_scatter_w(
  const int* bidx, int* wofs, int* elist, const int* rowstart, int* aLoTab)
{
  int gid = blockIdx.x*256 + threadIdx.x, gstride = gridDim.x*256;
  phase_scatter(gid,gstride,bidx,wofs,elist,rowstart,aLoTab);
}

__global__ __launch_bounds__(256, 2) void k_edge_w(
  const float* atom, const int* bidx, const float* bond,
  const unsigned short* Bh, const unsigned short* Bl,
  const int* elist, float* nbC)
{
  __shared__ float smem[6208];
  __shared__ int   sInt[64];
  phase_edge(threadIdx.x, blockIdx.x, atom,bidx,bond,Bh,Bl,elist,nbC,smem,sInt);
}

__global__ __launch_bounds__(256, 2) void k_win_w(
  const float* atom, const float* alW, const float* alB,
  const float* attWt, const float* attBf, const float* wT,
  const float* bih, const float* bhh,
  const int* rowstart, const int* aLoTab, const float* nbC, float* out)
{
  __shared__ float smem[6240];
  phase_window(threadIdx.x, blockIdx.x, atom,alW,alB,attWt,attBf,wT,bih,bhh,
               rowstart,aLoTab,nbC,out,smem);
}

extern "C" void kernel_launch(void* const* d_in, const int* in_sizes, int n_in,
                              void* d_out, int out_size, void* d_ws, size_t ws_size,
                              hipStream_t stream) {
  const float* atom = (const float*)d_in[0];
  const int*   bidx = (const int*)  d_in[1];
  const float* bond = (const float*)d_in[2];
  const float* encW = (const float*)d_in[3];
  const float* encB = (const float*)d_in[4];
  const float* eg   = (const float*)d_in[5];
  const float* ebt  = (const float*)d_in[6];
  const float* e_mn = (const float*)d_in[7];
  const float* e_vr = (const float*)d_in[8];
  const float* alW  = (const float*)d_in[9];
  const float* alB  = (const float*)d_in[10];
  const float* atW  = (const float*)d_in[11];
  const float* atB  = (const float*)d_in[12];
  const float* agm  = (const float*)d_in[13];
  const float* abt  = (const float*)d_in[14];
  const float* amn  = (const float*)d_in[15];
  const float* avr  = (const float*)d_in[16];
  const float* wih  = (const float*)d_in[17];
  const float* whh  = (const float*)d_in[18];
  const float* bih  = (const float*)d_in[19];
  const float* bhh  = (const float*)d_in[20];

  float* ws = (float*)d_ws;
  unsigned short* Bh = (unsigned short*)(ws + 0);       // 65536 ush
  unsigned short* Bl = (unsigned short*)(ws + 32768);   // 65536 ush
  float* attWt   = ws + 65536;    // 4096
  float* attBf   = ws + 69632;    // 64
  float* wT      = ws + 69696;    // 24576
  int*   cnt     = (int*)(ws + 94272);    // 10000
  int*   rowstart= (int*)(ws + 104272);   // 10001 (pad 10016)
  int*   wofs    = (int*)(ws + 114288);   // 10000
  int*   elist   = (int*)(ws + 124288);   // 40000
  int*   aLoTab  = (int*)(ws + 164288);   // 1251 (pad 1280)
  float* nbC     = ws + 165568;   // 2560000
  float* outp    = (float*)d_out;

  void* args[] = {
    (void*)&atom, (void*)&bidx, (void*)&bond,
    (void*)&encW, (void*)&encB, (void*)&eg, (void*)&ebt,
    (void*)&e_mn, (void*)&e_vr,
    (void*)&atW, (void*)&atB, (void*)&agm, (void*)&abt,
    (void*)&amn, (void*)&avr,
    (void*)&alW, (void*)&alB,
    (void*)&wih, (void*)&whh, (void*)&bih, (void*)&bhh,
    (void*)&Bh, (void*)&Bl, (void*)&attWt, (void*)&attBf, (void*)&wT,
    (void*)&cnt, (void*)&rowstart, (void*)&wofs, (void*)&elist, (void*)&aLoTab,
    (void*)&nbC, (void*)&outp
  };

  int maxb = 0;
  hipError_t qerr = hipOccupancyMaxActiveBlocksPerMultiprocessor(&maxb, (const void*)k_mega, 256, 0);
  int grid = (qerr == hipSuccess && maxb > 0) ? maxb*256 : 0;
  if (grid > 512) grid = 512;

  hipError_t err = hipErrorUnknown;
  if (grid >= 256)
    err = hipLaunchCooperativeKernel((void*)k_mega, dim3(grid), dim3(256), args, 0, stream);

  if (err != hipSuccess){
    hipMemsetAsync(cnt, 0, NA*sizeof(int), stream);
    k_pre_w<<<256, 256, 0, stream>>>(encW,encB,eg,ebt,e_mn,e_vr,atW,atB,agm,abt,amn,avr,
                                     wih,whh,bidx,Bh,Bl,attWt,attBf,wT,cnt);
    k_scan_w<<<1, 256, 0, stream>>>(cnt, rowstart, wofs);
    k_scatter_w<<<160, 256, 0, stream>>>(bidx, wofs, elist, rowstart, aLoTab);
    k_edge_w<<<NTILE, 256, 0, stream>>>(atom, bidx, bond, Bh, Bl, elist, nbC);
    k_win_w<<<NWIN, 256, 0, stream>>>(atom, alW, alB, attWt, attBf, wT, bih, bhh,
                                      rowstart, aLoTab, nbC, outp);
  }
}

// Round 7
// 224.121 us; speedup vs baseline: 2.4866x; 2.4866x over previous
//
#include <hip/hip_runtime.h>
#include <math.h>

#define NA 10000
#define NE 40000

typedef float f4 __attribute__((ext_vector_type(4)));
typedef float f16v __attribute__((ext_vector_type(16)));
typedef int   i4 __attribute__((ext_vector_type(4)));
typedef __bf16 bf16x8 __attribute__((ext_vector_type(8)));

union U8 { unsigned short us[8]; bf16x8 v; };

static __device__ __forceinline__ unsigned short bf_rne(float x){
  unsigned u = __float_as_uint(x);
  unsigned r = (u + 0x7fffu + ((u>>16)&1u)) >> 16;
  return (unsigned short)r;
}
static __device__ __forceinline__ float bf_to_f(unsigned short h){
  return __uint_as_float(((unsigned)h)<<16);
}

// ---------------- k_pre: fold BN into weights, tables, p[a], histogram ----------------
// Bh/Bl: enc GEMM B-operands for 32x32x16: [d(64)][ft(2)][lane(64)][j(8)] bf16.
//   k=(lane>>5)*8+j, n = d*64 + ft*32 + (lane&31)
//   k<12 -> Wfold[n][k] hi/lo; k==12 -> bias_fold[n] hi/lo; else 0
__global__ __launch_bounds__(256) void k_pre(
  const float* __restrict__ encW, const float* __restrict__ encB,
  const float* __restrict__ eg, const float* __restrict__ ebt,
  const float* __restrict__ e_mn, const float* __restrict__ e_vr,
  const float* __restrict__ attW, const float* __restrict__ attB,
  const float* __restrict__ agm, const float* __restrict__ abt,
  const float* __restrict__ amn, const float* __restrict__ avr,
  const float* __restrict__ wih, const float* __restrict__ whh,
  const int* __restrict__ bidx, const float* __restrict__ atom,
  const float* __restrict__ alW,
  unsigned short* __restrict__ Bh, unsigned short* __restrict__ Bl,
  float* __restrict__ attWt, float* __restrict__ attBf, float* __restrict__ wT,
  float* __restrict__ p, int* __restrict__ cnt)
{
  int tid = threadIdx.x;
  int gid = blockIdx.x*256 + tid;
  int gstride = gridDim.x*256;
  for (int i=gid; i<65536; i+=gstride){
    int j = i&7, ll = (i>>3)&63, t = i>>9;
    int d = t>>1, ft = t&1;
    int k = ((ll>>5)<<3)+j;
    int n = d*64 + ft*32 + (ll&31);
    float s = eg[n]*rsqrtf(e_vr[n]+1e-6f);
    unsigned short vh=0, vl=0;
    if (k<12){
      float wv = encW[n*12+k]*s;
      unsigned short hi = bf_rne(wv);
      vh = hi; vl = bf_rne(wv - bf_to_f(hi));
    } else if (k==12){
      float b = (encB[n]-e_mn[n])*s + ebt[n];
      unsigned short hi = bf_rne(b);
      vh = hi; vl = bf_rne(b - bf_to_f(hi));
    }
    Bh[i] = vh; Bl[i] = vl;
  }
  for (int i=gid; i<4096; i+=gstride){
    int k = i>>6, f = i&63;
    float s = agm[f]*rsqrtf(avr[f]+1e-6f);
    attWt[i] = attW[f*64+k]*s;
  }
  for (int f=gid; f<64; f+=gstride){
    float s = agm[f]*rsqrtf(avr[f]+1e-6f);
    attBf[f] = (attB[f]-amn[f])*s + abt[f];
  }
  // wT layout [g(6)][kg(16)][f(64)][j(4)]
  for (int i=gid; i<24576; i+=gstride){
    int j=i&3, f=(i>>2)&63, idx2=i>>8;
    int g=idx2>>4, kg=idx2&15, k=kg*4+j;
    wT[i] = (g<3)? wih[(g*64+f)*64+k] : whh[((g-3)*64+f)*64+k];
  }
  // p[a] = alW[0:64] . atom[a]
  {
    int wid = gid>>6;
    int l = tid&63;
    float wl = alW[l];
    for (int a=wid; a<NA; a+=(gstride>>6)){
      float v = wl*atom[(size_t)a*64+l];
      v += __shfl_xor(v,1);  v += __shfl_xor(v,2);
      v += __shfl_xor(v,4);  v += __shfl_xor(v,8);
      v += __shfl_xor(v,16); v += __shfl_xor(v,32);
      if (l==0) p[a]=v;
    }
  }
  for (int e=gid; e<NE; e+=gstride) atomicAdd(&cnt[bidx[e*2]],1);
}

// ---------------- k_scan: exclusive scan (single block, vectorized) ----------------
__global__ __launch_bounds__(256) void k_scan(const int* __restrict__ cnt,
                                              int* __restrict__ rowstart,
                                              int* __restrict__ wofs)
{
  __shared__ int sPart[256];
  int t = threadIdx.x;
  int base = t*40;           // 250 threads cover 10000
  i4 buf[10];
  int sum = 0;
  if (base < NA){
    const i4* cp = (const i4*)(cnt + base);
    #pragma unroll
    for (int i=0;i<10;i++) buf[i] = cp[i];
    #pragma unroll
    for (int i=0;i<10;i++) sum += buf[i].x+buf[i].y+buf[i].z+buf[i].w;
  }
  sPart[t]=sum;
  __syncthreads();
  for (int off=1; off<256; off<<=1){
    int v = (t>=off)? sPart[t-off] : 0;
    __syncthreads();
    sPart[t]+=v;
    __syncthreads();
  }
  int run = sPart[t]-sum;
  if (base < NA){
    #pragma unroll
    for (int i=0;i<10;i++){
      i4 b=buf[i], o;
      o.x=run; run+=b.x; o.y=run; run+=b.y;
      o.z=run; run+=b.z; o.w=run; run+=b.w;
      ((i4*)(rowstart+base))[i]=o;
      ((i4*)(wofs+base))[i]=o;
    }
  }
  if (t==0) rowstart[NA]=NE;
}

// ---------------- k_scatter: edges to CSR order ----------------
__global__ __launch_bounds__(256) void k_scatter(const int* __restrict__ bidx,
                                                 int* __restrict__ wofs,
                                                 int* __restrict__ elist)
{
  int e = blockIdx.x*256 + threadIdx.x;
  if (e < NE){
    int tg = bidx[e*2];
    int pos = atomicAdd(&wofs[tg],1);
    elist[pos]=e;
  }
}

// ---------------- k_edge: MFMA enc GEMM + contraction, 64 CSR edges/block ----------------
// 2 M-tiles of 32 edges share B-fragment loads; 4 waves split d (16 each);
// manual 1-deep prefetch of B fragments across the d loop.
__global__ __launch_bounds__(256) void k_edge(
  const float* __restrict__ atom, const int* __restrict__ bidx, const float* __restrict__ bond,
  const unsigned short* __restrict__ Bh, const unsigned short* __restrict__ Bl,
  const int* __restrict__ elist, float* __restrict__ nbC)
{
  __shared__ float sA[4352];    // atomT [d(64)][stride 68]  (17.4 KB)
  __shared__ float sP[8192];    // wave partials [w][mt][r][l] (32 KB)
  __shared__ int   sEl[64];
  __shared__ int   sNbr[64];

  int tid = threadIdx.x;
  int l = tid & 63;
  int w = tid >> 6;
  int g = l >> 5;
  int em = l & 31;
  int E0 = blockIdx.x * 64;    // 625 blocks * 64 = 40000

  if (tid < 64){
    int e = elist[E0+tid];
    sEl[tid] = e;
    sNbr[tid] = bidx[e*2+1];
  }
  __syncthreads();
  for (int i=tid; i<4096; i+=256){
    int le=i>>6, d=i&63;
    sA[d*68+le] = atom[(size_t)sNbr[le]*64 + d];
  }

  // A fragments for both M-tiles (edge = E0 + mt*32 + em), hi/lo split, bias k=12
  U8 A1[2], A2[2];
  #pragma unroll
  for (int mt=0; mt<2; mt++){
    const f4* bp = (const f4*)(bond + (size_t)sEl[mt*32+em]*12);
    f4 b0=bp[0], b1v=bp[1], b2v=bp[2];
    float bv[12] = {b0.x,b0.y,b0.z,b0.w,b1v.x,b1v.y,b1v.z,b1v.w,b2v.x,b2v.y,b2v.z,b2v.w};
    unsigned short hi[12], lo2[12];
    #pragma unroll
    for (int j=0;j<12;j++){ hi[j]=bf_rne(bv[j]); lo2[j]=bf_rne(bv[j]-bf_to_f(hi[j])); }
    #pragma unroll
    for (int j=0;j<8;j++){
      int k = g*8+j;
      A1[mt].us[j] = (k<12)? hi[k] : (k==12? (unsigned short)0x3F80 : (unsigned short)0);
      A2[mt].us[j] = (k<12)? lo2[k] : (unsigned short)0;
    }
  }
  __syncthreads();

  f4 nacc[2][2][4];   // [mt][ft][q]
  #pragma unroll
  for (int mt=0; mt<2; mt++)
    #pragma unroll
    for (int ft=0; ft<2; ft++)
      #pragma unroll
      for (int q=0;q<4;q++) nacc[mt][ft][q] = (f4){0.f,0.f,0.f,0.f};
  f16v cz;
  #pragma unroll
  for (int r=0;r<16;r++) cz[r] = 0.f;

  int dbase = w*16;
  U8 cbh0, cbl0, cbh1, cbl1;
  cbh0.v = *(const bf16x8*)(Bh + ((size_t)((dbase*2+0)*64 + l))*8);
  cbl0.v = *(const bf16x8*)(Bl + ((size_t)((dbase*2+0)*64 + l))*8);
  cbh1.v = *(const bf16x8*)(Bh + ((size_t)((dbase*2+1)*64 + l))*8);
  cbl1.v = *(const bf16x8*)(Bl + ((size_t)((dbase*2+1)*64 + l))*8);

  #pragma unroll 2
  for (int dd=0; dd<16; dd++){
    int d = dbase + dd;
    int dn = (dd<15)? d+1 : d;
    U8 nbh0, nbl0, nbh1, nbl1;
    nbh0.v = *(const bf16x8*)(Bh + ((size_t)((dn*2+0)*64 + l))*8);
    nbl0.v = *(const bf16x8*)(Bl + ((size_t)((dn*2+0)*64 + l))*8);
    nbh1.v = *(const bf16x8*)(Bh + ((size_t)((dn*2+1)*64 + l))*8);
    nbl1.v = *(const bf16x8*)(Bl + ((size_t)((dn*2+1)*64 + l))*8);

    #pragma unroll
    for (int mt=0; mt<2; mt++){
      f4 ldA[4];
      #pragma unroll
      for (int q=0;q<4;q++) ldA[q] = *(const f4*)&sA[d*68 + mt*32 + 8*q + 4*g];
      // ft = 0
      {
        f16v c;
        c = __builtin_amdgcn_mfma_f32_32x32x16_bf16(A1[mt].v, cbh0.v, cz, 0,0,0);
        c = __builtin_amdgcn_mfma_f32_32x32x16_bf16(A2[mt].v, cbh0.v, c, 0,0,0);
        c = __builtin_amdgcn_mfma_f32_32x32x16_bf16(A1[mt].v, cbl0.v, c, 0,0,0);
        #pragma unroll
        for (int r=0;r<16;r++){
          float ev = fmaxf(c[r], 0.f);
          nacc[mt][0][r>>2][r&3] = fmaf(ldA[r>>2][r&3], ev, nacc[mt][0][r>>2][r&3]);
        }
      }
      // ft = 1
      {
        f16v c;
        c = __builtin_amdgcn_mfma_f32_32x32x16_bf16(A1[mt].v, cbh1.v, cz, 0,0,0);
        c = __builtin_amdgcn_mfma_f32_32x32x16_bf16(A2[mt].v, cbh1.v, c, 0,0,0);
        c = __builtin_amdgcn_mfma_f32_32x32x16_bf16(A1[mt].v, cbl1.v, c, 0,0,0);
        #pragma unroll
        for (int r=0;r<16;r++){
          float ev = fmaxf(c[r], 0.f);
          nacc[mt][1][r>>2][r&3] = fmaf(ldA[r>>2][r&3], ev, nacc[mt][1][r>>2][r&3]);
        }
      }
    }
    cbh0 = nbh0; cbl0 = nbl0; cbh1 = nbh1; cbl1 = nbl1;
  }

  // two ft rounds: dump wave partials, reduce across 4 waves, write nbC (CSR order)
  #pragma unroll
  for (int ft=0; ft<2; ft++){
    __syncthreads();
    #pragma unroll
    for (int mt=0; mt<2; mt++)
      #pragma unroll
      for (int r=0;r<16;r++)
        sP[w*2048 + mt*1024 + r*64 + l] = nacc[mt][ft][r>>2][r&3];
    __syncthreads();
    for (int idx=tid; idx<2048; idx+=256){
      float v = sP[idx] + sP[2048+idx] + sP[4096+idx] + sP[6144+idx];
      int mt = idx>>10, rl = idx&1023;
      int r = rl>>6, ll = rl&63;
      int m = mt*32 + (r&3) + ((r>>2)<<3) + ((ll>>5)<<2);
      int f = (ft<<5) + (ll&31);
      nbC[(size_t)(E0+m)*64 + f] = v;
    }
  }
}

// ---------------- k_gru: fused per-atom softmax + context + ELU + GRU ----------------
// 313 blocks x 32 atoms; wave per 8 atoms; edges CSR-contiguous in nbC.
__global__ __launch_bounds__(256) void k_gru(
  const float* __restrict__ atom, const float* __restrict__ nbC,
  const int* __restrict__ rowstart, const float* __restrict__ p,
  const float* __restrict__ alW, const float* __restrict__ alB,
  const float* __restrict__ attWt, const float* __restrict__ attBf,
  const float* __restrict__ wT,
  const float* __restrict__ bih, const float* __restrict__ bhh,
  float* __restrict__ out)
{
  __shared__ float sc[4][8][64];
  __shared__ float shh[4][8][64];
  __shared__ float sW[4096];
  int tid = threadIdx.x;
  int l = tid & 63;
  int w = tid >> 6;
  for (int i=tid; i<4096; i+=256) sW[i] = attWt[i];
  __syncthreads();

  int base = blockIdx.x*32 + w*8;
  float alwn = alW[64+l];
  float ab = alB[0];
  float bfv = attBf[l];

  for (int a8=0; a8<8; a8++){
    int a = base + a8;
    float cf=0.f, hf=0.f;
    if (a < NA){
      hf = atom[(size_t)a*64 + l];
      int d0 = rowstart[a];
      int deg = rowstart[a+1] - d0;
      if (deg > 0){
        float pa = p[a];
        // pass 1: max of scores
        float mx = -1e30f;
        for (int i=0;i<deg;i++){
          float r = nbC[(size_t)(d0+i)*64 + l];
          float q = r*alwn;
          q += __shfl_xor(q,1);  q += __shfl_xor(q,2);
          q += __shfl_xor(q,4);  q += __shfl_xor(q,8);
          q += __shfl_xor(q,16); q += __shfl_xor(q,32);
          float s = pa + q + ab;
          s = (s>0.f)? s : 0.01f*s;
          mx = fmaxf(mx, s);
        }
        // pass 2: exp, denom, y accumulation (rows L1/L2-hot)
        float dn = 0.f, y = 0.f;
        for (int i=0;i<deg;i++){
          float r = nbC[(size_t)(d0+i)*64 + l];
          float q = r*alwn;
          q += __shfl_xor(q,1);  q += __shfl_xor(q,2);
          q += __shfl_xor(q,4);  q += __shfl_xor(q,8);
          q += __shfl_xor(q,16); q += __shfl_xor(q,32);
          float s = pa + q + ab;
          s = (s>0.f)? s : 0.01f*s;
          float ex = __expf(s - mx);
          dn += ex;
          y = fmaf(ex, r, y);
        }
        float ctx = dn * bfv;
        #pragma unroll 8
        for (int k=0;k<64;k++)
          ctx = fmaf(__shfl(y,k), sW[k*64 + l], ctx);
        cf = ctx / (dn + 1e-8f);
        cf = (cf>0.f)? cf : expm1f(cf);
      }
    }
    sc[w][a8][l] = cf; shh[w][a8][l] = hf;
  }
  __syncthreads();

  float acc[6][8];
  #pragma unroll
  for (int gg=0;gg<6;gg++)
    #pragma unroll
    for (int a=0;a<8;a++) acc[gg][a] = 0.f;

  for (int kg=0; kg<16; kg++){
    f4 wv[6];
    #pragma unroll
    for (int gg=0;gg<6;gg++) wv[gg] = *(const f4*)&wT[(size_t)((gg*16+kg)*64 + l)*4];
    #pragma unroll
    for (int a=0;a<8;a++){
      f4 cv = *(const f4*)&sc[w][a][kg*4];
      f4 hv = *(const f4*)&shh[w][a][kg*4];
      #pragma unroll
      for (int j=0;j<4;j++){
        acc[0][a] = fmaf(cv[j], wv[0][j], acc[0][a]);
        acc[1][a] = fmaf(cv[j], wv[1][j], acc[1][a]);
        acc[2][a] = fmaf(cv[j], wv[2][j], acc[2][a]);
        acc[3][a] = fmaf(hv[j], wv[3][j], acc[3][a]);
        acc[4][a] = fmaf(hv[j], wv[4][j], acc[4][a]);
        acc[5][a] = fmaf(hv[j], wv[5][j], acc[5][a]);
      }
    }
  }

  float b0 = bih[l], b1 = bih[64+l], b2 = bih[128+l];
  float h0 = bhh[l], h1 = bhh[64+l], h2 = bhh[128+l];
  #pragma unroll
  for (int a=0;a<8;a++){
    int ga = base + a;
    if (ga < NA){
      float hf = shh[w][a][l];
      float r = 1.f/(1.f + expf(-(acc[0][a] + b0 + acc[3][a] + h0)));
      float z = 1.f/(1.f + expf(-(acc[1][a] + b1 + acc[4][a] + h1)));
      float n = tanhf(acc[2][a] + b2 + r*(acc[5][a] + h2));
      out[(size_t)ga*64 + l] = (1.f - z)*n + z*hf;
    }
  }
}

extern "C" void kernel_launch(void* const* d_in, const int* in_sizes, int n_in,
                              void* d_out, int out_size, void* d_ws, size_t ws_size,
                              hipStream_t stream) {
  const float* atom = (const float*)d_in[0];
  const int*   bidx = (const int*)  d_in[1];
  const float* bond = (const float*)d_in[2];
  const float* encW = (const float*)d_in[3];
  const float* encB = (const float*)d_in[4];
  const float* eg   = (const float*)d_in[5];
  const float* ebt  = (const float*)d_in[6];
  const float* e_mn = (const float*)d_in[7];
  const float* e_vr = (const float*)d_in[8];
  const float* alW  = (const float*)d_in[9];
  const float* alB  = (const float*)d_in[10];
  const float* atW  = (const float*)d_in[11];
  const float* atB  = (const float*)d_in[12];
  const float* agm  = (const float*)d_in[13];
  const float* abt  = (const float*)d_in[14];
  const float* amn  = (const float*)d_in[15];
  const float* avr  = (const float*)d_in[16];
  const float* wih  = (const float*)d_in[17];
  const float* whh  = (const float*)d_in[18];
  const float* bih  = (const float*)d_in[19];
  const float* bhh  = (const float*)d_in[20];

  float* ws = (float*)d_ws;
  unsigned short* Bh = (unsigned short*)(ws + 0);       // 65536 ush
  unsigned short* Bl = (unsigned short*)(ws + 32768);   // 65536 ush
  float* attWt   = ws + 65536;    // 4096
  float* attBf   = ws + 69632;    // 64
  float* wT      = ws + 69696;    // 24576
  float* p       = ws + 94272;    // 10016
  int*   cnt     = (int*)(ws + 104288);   // 10016
  int*   rowstart= (int*)(ws + 114304);   // 10016 (10001 used)
  int*   wofs    = (int*)(ws + 124320);   // 10016
  int*   elist   = (int*)(ws + 134336);   // 40000
  float* nbC     = ws + 174336;   // 2560000
  float* outp    = (float*)d_out;

  hipMemsetAsync(cnt, 0, NA*sizeof(int), stream);
  k_pre<<<512, 256, 0, stream>>>(encW,encB,eg,ebt,e_mn,e_vr,
                                 atW,atB,agm,abt,amn,avr,
                                 wih,whh,bidx,atom,alW,
                                 Bh,Bl,attWt,attBf,wT,p,cnt);
  k_scan<<<1, 256, 0, stream>>>(cnt, rowstart, wofs);
  k_scatter<<<(NE+255)/256, 256, 0, stream>>>(bidx, wofs, elist);
  k_edge<<<625, 256, 0, stream>>>(atom, bidx, bond, Bh, Bl, elist, nbC);
  k_gru<<<313, 256, 0, stream>>>(atom, nbC, rowstart, p, alW, alB,
                                 attWt, attBf, wT, bih, bhh, outp);
}